// Round 3
// baseline (14658.994 us; speedup 1.0000x reference)
//
#include <hip/hip_runtime.h>
#include <hip/hip_bf16.h>

typedef __hip_bfloat16 bf16;

#define DM   768
#define NH   12
#define DH   64
#define DFF  3072
#define TS   4096
#define NB   2
#define MTOK (NB * TS)   // 8192 tokens
#define EPS  1e-5f

__device__ __forceinline__ float b2f(bf16 v)  { return __bfloat162float(v); }
__device__ __forceinline__ bf16  f2b(float v) { return __float2bfloat16(v); }

__device__ __forceinline__ float ldf(const float* p) { return *p; }
__device__ __forceinline__ float ldf(const bf16*  p) { return b2f(*p); }

__device__ __forceinline__ void stf(float* p, float v) { *p = v; }
__device__ __forceinline__ void stf(bf16*  p, float v) { *p = f2b(v); }

// ---------------------------------------------------------------------------
// GEMM: C[M,N] = act(A[M,K] @ W[K,N] + bias[N]) ; A fp32-or-bf16, W/bias fp32,
// C bf16, fp32 accumulate. 64x64 tile, BK=16, 256 threads, 4x4 micro-tile.
// ---------------------------------------------------------------------------
template <int RELU, typename TA>
__global__ __launch_bounds__(256)
void gemm_bias(const TA* __restrict__ A, const float* __restrict__ W,
               const float* __restrict__ bias, bf16* __restrict__ C,
               int M, int N, int K)
{
    constexpr int BM = 64, BN = 64, BK = 16;
    __shared__ float As[BK][BM + 4];   // [k][m]
    __shared__ float Bs[BK][BN + 4];   // [k][n]

    const int tid = threadIdx.x;
    const int tx = tid & 15;          // N micro
    const int ty = tid >> 4;          // M micro
    const int bm = blockIdx.y * BM;
    const int bn = blockIdx.x * BN;

    float acc[4][4] = {};

    for (int k0 = 0; k0 < K; k0 += BK) {
        #pragma unroll
        for (int j = 0; j < 4; ++j) {
            int idx = tid * 4 + j;          // 0..1023
            int r = idx >> 4, c = idx & 15;
            As[c][r] = ldf(A + (size_t)(bm + r) * K + k0 + c);
        }
        #pragma unroll
        for (int j = 0; j < 4; ++j) {
            int idx = tid * 4 + j;
            int r = idx >> 6, c = idx & 63;
            Bs[r][c] = W[(size_t)(k0 + r) * N + bn + c];
        }
        __syncthreads();

        #pragma unroll
        for (int kk = 0; kk < BK; ++kk) {
            float av[4], bv[4];
            #pragma unroll
            for (int i = 0; i < 4; ++i) av[i] = As[kk][ty * 4 + i];
            #pragma unroll
            for (int j = 0; j < 4; ++j) bv[j] = Bs[kk][tx * 4 + j];
            #pragma unroll
            for (int i = 0; i < 4; ++i)
                #pragma unroll
                for (int j = 0; j < 4; ++j)
                    acc[i][j] += av[i] * bv[j];
        }
        __syncthreads();
    }

    #pragma unroll
    for (int i = 0; i < 4; ++i) {
        const size_t r = (size_t)(bm + ty * 4 + i);
        #pragma unroll
        for (int j = 0; j < 4; ++j) {
            const int cidx = bn + tx * 4 + j;
            float v = acc[i][j] + bias[cidx];
            if (RELU) v = fmaxf(v, 0.f);
            C[r * N + cidx] = f2b(v);
        }
    }
}

// ---------------------------------------------------------------------------
// Causal flash attention, one wave per (b, h, q) row. Lane d owns head-dim d.
// Online softmax in fp32; l >= 1 after first key so no zero-div.
// ---------------------------------------------------------------------------
__global__ __launch_bounds__(64)
void attn_flash(const bf16* __restrict__ Q, const bf16* __restrict__ K,
                const bf16* __restrict__ V, bf16* __restrict__ O)
{
    const int gid  = blockIdx.x;              // (b*NH + h)*TS + q
    const int q    = gid & (TS - 1);
    const int hb   = gid >> 12;               // TS = 4096 = 2^12
    const int h    = hb % NH;
    const int b    = hb / NH;
    const int lane = threadIdx.x;

    const size_t head_base = (size_t)b * TS * DM + (size_t)h * DH + lane;

    const float qv = b2f(Q[head_base + (size_t)q * DM]) * 0.125f; // 1/sqrt(64)

    float m = -1e30f, l = 0.f, acc = 0.f;
    for (int k = 0; k <= q; ++k) {
        const size_t off = head_base + (size_t)k * DM;
        float s = qv * b2f(K[off]);
        #pragma unroll
        for (int d = 32; d > 0; d >>= 1) s += __shfl_xor(s, d, 64);
        const float mn = fmaxf(m, s);
        const float p  = __expf(s - mn);
        const float cr = __expf(m - mn);
        const float vv = b2f(V[off]);
        l   = l * cr + p;
        acc = acc * cr + p * vv;
        m   = mn;
    }
    O[head_base + (size_t)q * DM] = f2b(acc / l);
}

// ---------------------------------------------------------------------------
// Fused residual-add + LayerNorm: out = LN(a + r) * gamma + beta
// One 256-thread block per token row (768 = 3 * 256). TOUT = float or bf16.
// ---------------------------------------------------------------------------
template <typename T1, typename T2, typename TOUT>
__global__ __launch_bounds__(256)
void add_ln(const T1* __restrict__ a, const T2* __restrict__ r,
            const float* __restrict__ gamma, const float* __restrict__ beta,
            TOUT* __restrict__ out)
{
    const int row = blockIdx.x;
    const size_t off = (size_t)row * DM;
    const int tid = threadIdx.x;

    float v[3];
    float s = 0.f, s2 = 0.f;
    #pragma unroll
    for (int j = 0; j < 3; ++j) {
        const int i = tid + j * 256;
        const float t = ldf(a + off + i) + ldf(r + off + i);
        v[j] = t; s += t; s2 += t * t;
    }

    __shared__ float red[256], red2[256];
    red[tid] = s; red2[tid] = s2;
    __syncthreads();
    #pragma unroll
    for (int st = 128; st > 0; st >>= 1) {
        if (tid < st) { red[tid] += red[tid + st]; red2[tid] += red2[tid + st]; }
        __syncthreads();
    }
    const float mu   = red[0] * (1.f / DM);
    const float var  = red2[0] * (1.f / DM) - mu * mu;   // biased, matches jnp.var
    const float rstd = rsqrtf(var + EPS);

    #pragma unroll
    for (int j = 0; j < 3; ++j) {
        const int i = tid + j * 256;
        stf(out + off + i, (v[j] - mu) * rstd * gamma[i] + beta[i]);
    }
}

// ---------------------------------------------------------------------------
extern "C" void kernel_launch(void* const* d_in, const int* in_sizes, int n_in,
                              void* d_out, int out_size, void* d_ws, size_t ws_size,
                              hipStream_t stream)
{
    (void)in_sizes; (void)n_in; (void)out_size;

    // Inputs fp32 per the reference (jnp.float32); output fp32 as well.
    const float* x   = (const float*)d_in[0];
    const float* wq  = (const float*)d_in[1];  const float* bq  = (const float*)d_in[2];
    const float* wk  = (const float*)d_in[3];  const float* bk  = (const float*)d_in[4];
    const float* wv  = (const float*)d_in[5];  const float* bv  = (const float*)d_in[6];
    const float* wo  = (const float*)d_in[7];  const float* bo  = (const float*)d_in[8];
    const float* w1  = (const float*)d_in[9];  const float* b1  = (const float*)d_in[10];
    const float* w2  = (const float*)d_in[11]; const float* b2  = (const float*)d_in[12];
    const float* g1  = (const float*)d_in[13]; const float* be1 = (const float*)d_in[14];
    const float* g2  = (const float*)d_in[15]; const float* be2 = (const float*)d_in[16];

    // Workspace (bf16 elements). S = one [8192,768] buffer = 6.29M elems.
    // Layout: Q K V A H (5S) + F1 chunk (CH x 3072). CH from ws_size —
    // ws_size is constant across calls, so this branch is graph-capture safe.
    const size_t S = (size_t)MTOK * DM;
    const size_t elems_avail = ws_size / sizeof(bf16);
    int CH = MTOK;                                               // 113 MiB
    if (elems_avail < 5 * S + (size_t)MTOK * DFF) CH = 2048;     //  75 MiB
    if (elems_avail < 5 * S + (size_t)2048 * DFF) CH = 512;      //  66 MiB
    if (elems_avail < 5 * S + (size_t)512  * DFF) CH = 128;      //  64 MiB

    bf16* Qb = (bf16*)d_ws;
    bf16* Kb = Qb + S;
    bf16* Vb = Kb + S;
    bf16* Ab = Vb + S;
    bf16* Hb = Ab + S;
    bf16* F1 = Hb + S;           // [CH, 3072]
    bf16* Pb = Qb;               // attn projection out (Q dead after attn)
    bf16* Yb = Kb;               // ffn2 out (K dead after attn)

    const dim3 blk(256);
    const dim3 g768(DM / 64, MTOK / 64);    // (12, 128)

    gemm_bias<0, float><<<g768, blk, 0, stream>>>(x,  wq, bq, Qb, MTOK, DM, DM);
    gemm_bias<0, float><<<g768, blk, 0, stream>>>(x,  wk, bk, Kb, MTOK, DM, DM);
    gemm_bias<0, float><<<g768, blk, 0, stream>>>(x,  wv, bv, Vb, MTOK, DM, DM);

    attn_flash<<<dim3(NB * NH * TS), dim3(64), 0, stream>>>(Qb, Kb, Vb, Ab);

    gemm_bias<0, bf16><<<g768, blk, 0, stream>>>(Ab, wo, bo, Pb, MTOK, DM, DM);
    add_ln<float, bf16, bf16><<<dim3(MTOK), blk, 0, stream>>>(x, Pb, g1, be1, Hb);

    for (int m0 = 0; m0 < MTOK; m0 += CH) {
        gemm_bias<1, bf16><<<dim3(DFF / 64, CH / 64), blk, 0, stream>>>(
            Hb + (size_t)m0 * DM, w1, b1, F1, CH, DFF, DM);
        gemm_bias<0, bf16><<<dim3(DM / 64, CH / 64), blk, 0, stream>>>(
            F1, w2, b2, Yb + (size_t)m0 * DM, CH, DM, DFF);
    }

    add_ln<bf16, bf16, float><<<dim3(MTOK), blk, 0, stream>>>(
        Hb, Yb, g2, be2, (float*)d_out);
}

// Round 6
// 13512.953 us; speedup vs baseline: 1.0848x; 1.0848x over previous
//
#include <hip/hip_runtime.h>
#include <hip/hip_bf16.h>

typedef __hip_bfloat16 bf16;
typedef __attribute__((ext_vector_type(8))) short short8;
typedef __attribute__((ext_vector_type(4))) float floatx4;

#define DM   768
#define NH   12
#define DH   64
#define DFF  3072
#define TS   4096
#define NB   2
#define MTOK (NB * TS)   // 8192 tokens
#define EPS  1e-5f

__device__ __forceinline__ float b2f(bf16 v)  { return __bfloat162float(v); }
__device__ __forceinline__ bf16  f2b(float v) { return __float2bfloat16(v); }
__device__ __forceinline__ short sbf(float x) { bf16 b = __float2bfloat16(x); return *(short*)&b; }

__device__ __forceinline__ float ldf(const float* p) { return *p; }
__device__ __forceinline__ float ldf(const bf16*  p) { return b2f(*p); }
__device__ __forceinline__ void stf(float* p, float v) { *p = v; }
__device__ __forceinline__ void stf(bf16*  p, float v) { *p = f2b(v); }

// ---------------------------------------------------------------------------
// MFMA GEMM (UNCHANGED from round 5 — under test this round).
// C[M,N] = act(A[.,K] @ W[K,N] + bias[N]); Wt[N][K] bf16; A fp32 or bf16.
// 128x128 tile, BK=32, 4 waves (2x2), wave 64x64 via 4x4 of 16x16x32 MFMA.
// ---------------------------------------------------------------------------
template <int RELU, typename TA>
__global__ __launch_bounds__(256)
void gemm_mfma(const TA* __restrict__ A, int lda, const bf16* __restrict__ Wt,
               const float* __restrict__ bias, bf16* __restrict__ C, int ldc,
               int N, int K)
{
    constexpr int LDT = 40;
    __shared__ __align__(16) short As[128 * LDT];
    __shared__ __align__(16) short Bs[128 * LDT];

    const int tid  = threadIdx.x;
    const int wave = tid >> 6, lane = tid & 63;
    const int wx = wave & 1, wy = wave >> 1;
    const int quad = lane >> 4, fn = lane & 15;
    const int bm = blockIdx.y * 128, bn = blockIdx.x * 128;

    floatx4 acc[4][4] = {};

    const int sr = tid >> 2, sc8 = (tid & 3) * 8;

    for (int kk = 0; kk < K; kk += 32) {
        __syncthreads();
        if constexpr (sizeof(TA) == 2) {
            *(short8*)&As[sr * LDT + sc8] =
                *(const short8*)&A[(size_t)(bm + sr) * lda + kk + sc8];
            *(short8*)&As[(sr + 64) * LDT + sc8] =
                *(const short8*)&A[(size_t)(bm + sr + 64) * lda + kk + sc8];
        } else {
            const float* p0 = (const float*)A + (size_t)(bm + sr) * lda + kk + sc8;
            const float* p1 = (const float*)A + (size_t)(bm + sr + 64) * lda + kk + sc8;
            float4 a0 = *(const float4*)p0, a1 = *(const float4*)(p0 + 4);
            float4 c0 = *(const float4*)p1, c1 = *(const float4*)(p1 + 4);
            short8 v0, v1;
            v0[0]=sbf(a0.x); v0[1]=sbf(a0.y); v0[2]=sbf(a0.z); v0[3]=sbf(a0.w);
            v0[4]=sbf(a1.x); v0[5]=sbf(a1.y); v0[6]=sbf(a1.z); v0[7]=sbf(a1.w);
            v1[0]=sbf(c0.x); v1[1]=sbf(c0.y); v1[2]=sbf(c0.z); v1[3]=sbf(c0.w);
            v1[4]=sbf(c1.x); v1[5]=sbf(c1.y); v1[6]=sbf(c1.z); v1[7]=sbf(c1.w);
            *(short8*)&As[sr * LDT + sc8] = v0;
            *(short8*)&As[(sr + 64) * LDT + sc8] = v1;
        }
        *(short8*)&Bs[sr * LDT + sc8] =
            *(const short8*)&Wt[(size_t)(bn + sr) * K + kk + sc8];
        *(short8*)&Bs[(sr + 64) * LDT + sc8] =
            *(const short8*)&Wt[(size_t)(bn + sr + 64) * K + kk + sc8];
        __syncthreads();

        short8 af[4], bfr[4];
        #pragma unroll
        for (int i = 0; i < 4; ++i) {
            af[i]  = *(const short8*)&As[(wy * 64 + i * 16 + fn) * LDT + quad * 8];
            bfr[i] = *(const short8*)&Bs[(wx * 64 + i * 16 + fn) * LDT + quad * 8];
        }
        #pragma unroll
        for (int i = 0; i < 4; ++i)
            #pragma unroll
            for (int j = 0; j < 4; ++j)
                acc[i][j] = __builtin_amdgcn_mfma_f32_16x16x32_bf16(
                    af[i], bfr[j], acc[i][j], 0, 0, 0);
    }

    #pragma unroll
    for (int j = 0; j < 4; ++j) {
        const int n = bn + wx * 64 + j * 16 + fn;
        const float bv = bias[n];
        #pragma unroll
        for (int i = 0; i < 4; ++i) {
            #pragma unroll
            for (int rg = 0; rg < 4; ++rg) {
                const int m = bm + wy * 64 + i * 16 + quad * 4 + rg;
                float v = acc[i][j][rg] + bv;
                if (RELU) v = fmaxf(v, 0.f);
                C[(size_t)m * ldc + n] = f2b(v);
            }
        }
    }
}

// ---------------------------------------------------------------------------
// Scalar flash attention (round-3-PROVEN algorithm, ported to packed QKV).
// One wave per (b,h,q) row; lane d owns head-dim d. QKV [tok][2304]:
// Q at h*64, K at 768+h*64, V at 1536+h*64. Output in-place into Q-band
// (each wave reads/writes only its own Q element; K/V never written).
// ---------------------------------------------------------------------------
__global__ __launch_bounds__(64)
void attn_scalar(bf16* __restrict__ QKV)
{
    const int gid  = blockIdx.x;              // (b*NH + h)*TS + q
    const int q    = gid & (TS - 1);
    const int hb   = gid >> 12;
    const int h    = hb % NH;
    const int b    = hb / NH;
    const int lane = threadIdx.x;

    const size_t rowbase = (size_t)(b * TS) * 2304 + h * 64 + lane;

    const float qv = b2f(QKV[rowbase + (size_t)q * 2304]) * 0.125f;

    float m = -1e30f, l = 0.f, acc = 0.f;
    for (int k = 0; k <= q; ++k) {
        const size_t off = rowbase + (size_t)k * 2304;
        float s = qv * b2f(QKV[off + 768]);
        #pragma unroll
        for (int d = 32; d > 0; d >>= 1) s += __shfl_xor(s, d, 64);
        const float mn = fmaxf(m, s);
        const float p  = __expf(s - mn);
        const float cr = __expf(m - mn);
        const float vv = b2f(QKV[off + 1536]);
        l   = l * cr + p;
        acc = acc * cr + p * vv;
        m   = mn;
    }
    QKV[rowbase + (size_t)q * 2304] = f2b(acc / l);
}

// ---------------------------------------------------------------------------
// Weight convert+transpose: Wt[n][k] = bf16(W[k][n]).
// ---------------------------------------------------------------------------
__global__ __launch_bounds__(256)
void transW(const float* __restrict__ W, bf16* __restrict__ Wt, int K, int N)
{
    __shared__ float t[32][33];
    const int k0 = blockIdx.x * 32, n0 = blockIdx.y * 32;
    const int tx = threadIdx.x, ty = threadIdx.y;
    #pragma unroll
    for (int i = 0; i < 4; ++i)
        t[ty + i * 8][tx] = W[(size_t)(k0 + ty + i * 8) * N + n0 + tx];
    __syncthreads();
    #pragma unroll
    for (int i = 0; i < 4; ++i)
        Wt[(size_t)(n0 + ty + i * 8) * K + k0 + tx] = f2b(t[tx][ty + i * 8]);
}

__global__ __launch_bounds__(256)
void pack_bias(const float* __restrict__ bq, const float* __restrict__ bk,
               const float* __restrict__ bv, float* __restrict__ out)
{
    const int i = blockIdx.x * 256 + threadIdx.x;
    if (i < 3 * DM)
        out[i] = (i < DM) ? bq[i] : (i < 2 * DM) ? bk[i - DM] : bv[i - 2 * DM];
}

// ---------------------------------------------------------------------------
// Fused residual-add + LayerNorm; r has row-stride ldr.
// ---------------------------------------------------------------------------
template <typename T1, typename T2, typename TOUT>
__global__ __launch_bounds__(256)
void add_ln(const T1* __restrict__ a, const T2* __restrict__ r, int ldr,
            const float* __restrict__ gamma, const float* __restrict__ beta,
            TOUT* __restrict__ out)
{
    const int row = blockIdx.x;
    const size_t offa = (size_t)row * DM;
    const size_t offr = (size_t)row * ldr;
    const int tid = threadIdx.x;

    float v[3];
    float s = 0.f, s2 = 0.f;
    #pragma unroll
    for (int j = 0; j < 3; ++j) {
        const int i = tid + j * 256;
        const float t = ldf(a + offa + i) + ldf(r + offr + i);
        v[j] = t; s += t; s2 += t * t;
    }
    __shared__ float red[256], red2[256];
    red[tid] = s; red2[tid] = s2;
    __syncthreads();
    #pragma unroll
    for (int st = 128; st > 0; st >>= 1) {
        if (tid < st) { red[tid] += red[tid + st]; red2[tid] += red2[tid + st]; }
        __syncthreads();
    }
    const float mu   = red[0] * (1.f / DM);
    const float var  = red2[0] * (1.f / DM) - mu * mu;
    const float rstd = rsqrtf(var + EPS);
    #pragma unroll
    for (int j = 0; j < 3; ++j) {
        const int i = tid + j * 256;
        stf(out + offa + i, (v[j] - mu) * rstd * gamma[i] + beta[i]);
    }
}

// ---------------------------------------------------------------------------
extern "C" void kernel_launch(void* const* d_in, const int* in_sizes, int n_in,
                              void* d_out, int out_size, void* d_ws, size_t ws_size,
                              hipStream_t stream)
{
    (void)in_sizes; (void)n_in; (void)out_size; (void)ws_size;

    const float* x   = (const float*)d_in[0];
    const float* wq  = (const float*)d_in[1];  const float* bq  = (const float*)d_in[2];
    const float* wk  = (const float*)d_in[3];  const float* bk  = (const float*)d_in[4];
    const float* wv  = (const float*)d_in[5];  const float* bv  = (const float*)d_in[6];
    const float* wo  = (const float*)d_in[7];  const float* bo  = (const float*)d_in[8];
    const float* w1  = (const float*)d_in[9];  const float* b1  = (const float*)d_in[10];
    const float* w2  = (const float*)d_in[11]; const float* b2  = (const float*)d_in[12];
    const float* g1  = (const float*)d_in[13]; const float* be1 = (const float*)d_in[14];
    const float* g2  = (const float*)d_in[15]; const float* be2 = (const float*)d_in[16];

    // ws layout (bf16 elems), ~59.8 MB (same as round 5):
    //   QKVb [8192][2304] = 3S | Hb = S | wbuf = 2*DFF*DM | bqkv fp32[2304]
    const size_t S = (size_t)MTOK * DM;
    bf16* QKVb = (bf16*)d_ws;
    bf16* Hb   = QKVb + 3 * S;
    bf16* wbuf = Hb + S;
    float* bqkv = (float*)(wbuf + (size_t)2 * DFF * DM);
    bf16* F1 = QKVb;              // [4096][3072] chunk
    bf16* Yb = QKVb + 2 * S;
    bf16* AttnO = QKVb;           // Q-band, lda 2304
    bf16* Pb = QKVb + DM;         // K-band, ldc/ldr 2304

    const dim3 tblk(32, 8);
    const dim3 blk(256);

    // QKV projection
    transW<<<dim3(24, 24), tblk, 0, stream>>>(wq, wbuf,                    DM, DM);
    transW<<<dim3(24, 24), tblk, 0, stream>>>(wk, wbuf + (size_t)DM * DM,  DM, DM);
    transW<<<dim3(24, 24), tblk, 0, stream>>>(wv, wbuf + (size_t)2*DM*DM,  DM, DM);
    pack_bias<<<dim3(9), blk, 0, stream>>>(bq, bk, bv, bqkv);
    gemm_mfma<0, float><<<dim3(18, 64), blk, 0, stream>>>(
        x, DM, wbuf, bqkv, QKVb, 3 * DM, 3 * DM, DM);

    // attention — PROVEN scalar kernel (bisection round: isolates gemm_mfma)
    attn_scalar<<<dim3(NB * NH * TS), dim3(64), 0, stream>>>(QKVb);

    // O-projection (Q-band -> K-band), then LN1 -> Hb
    transW<<<dim3(24, 24), tblk, 0, stream>>>(wo, wbuf, DM, DM);
    gemm_mfma<0, bf16><<<dim3(6, 64), blk, 0, stream>>>(
        AttnO, 3 * DM, wbuf, bo, Pb, 3 * DM, DM, DM);
    add_ln<float, bf16, bf16><<<dim3(MTOK), blk, 0, stream>>>(
        x, Pb, 3 * DM, g1, be1, Hb);

    // FFN (chunked over M; F1/Yb live in the dead QKVb region)
    transW<<<dim3(24, 96), tblk, 0, stream>>>(w1, wbuf, DM, DFF);
    bf16* w2t = wbuf + (size_t)DFF * DM;
    transW<<<dim3(96, 24), tblk, 0, stream>>>(w2, w2t, DFF, DM);
    for (int m0 = 0; m0 < MTOK; m0 += 4096) {
        gemm_mfma<1, bf16><<<dim3(24, 32), blk, 0, stream>>>(
            Hb + (size_t)m0 * DM, DM, wbuf, b1, F1, DFF, DFF, DM);
        gemm_mfma<0, bf16><<<dim3(6, 32), blk, 0, stream>>>(
            F1, DFF, w2t, b2, Yb + (size_t)m0 * DM, DM, DM, DFF);
    }

    add_ln<bf16, bf16, float><<<dim3(MTOK), blk, 0, stream>>>(
        Hb, Yb, DM, g2, be2, (float*)d_out);
}